// Round 7
// baseline (204.657 us; speedup 1.0000x reference)
//
#include <hip/hip_runtime.h>

typedef unsigned short u16;
typedef unsigned int u32;
typedef short short8 __attribute__((ext_vector_type(8)));
typedef float f32x4 __attribute__((ext_vector_type(4)));

#define N_B 2
#define N_L 2048
#define N_D 1024
#define N_H 16
#define N_KVH 4
#define HDIM 64
#define WINDOW 1024

// log2(e) folded into Q so softmax can use exp2 directly
#define QSCALE (0.125f * 1.44269504088896f)

__device__ __forceinline__ u16 f2bf(float f) {
  unsigned u = __builtin_bit_cast(unsigned, f);
  u = u + 0x7fffu + ((u >> 16) & 1u);
  return (u16)(u >> 16);
}

// pack two f32 -> (bf16(hi)<<16)|bf16(lo), round-half-up, one v_perm
__device__ __forceinline__ u32 pk2bf(float lo, float hi) {
  u32 a = __builtin_bit_cast(u32, lo) + 0x8000u;
  u32 b = __builtin_bit_cast(u32, hi) + 0x8000u;
  return __builtin_amdgcn_perm(b, a, 0x07060302u);
}

// async global->LDS, 16B per lane. LDS dest must be wave-uniform base + lane*16.
__device__ __forceinline__ void gl2lds16(const u16* g, u16* l) {
  __builtin_amdgcn_global_load_lds((const __attribute__((address_space(1))) void*)g,
                                   (__attribute__((address_space(3))) void*)l, 16, 0, 0);
}

// ---------------- fused prep: convert x, transpose 4 weights, rope ----------------
// (r6 verbatim known-good version)

__global__ __launch_bounds__(256) void prep_kernel(
    const float* __restrict__ x, const float* __restrict__ Wq, const float* __restrict__ Wk,
    const float* __restrict__ Wv, const float* __restrict__ Wo,
    u16* __restrict__ xb, u16* __restrict__ wqkvT, u16* __restrict__ woT,
    float* __restrict__ rc, float* __restrict__ rs) {
  __shared__ float tbuf[32][33];
  int bid = blockIdx.x, tid = threadIdx.x;
  if (bid < 1024) {  // x fp32 -> bf16, 16 elems/thread
    size_t base = ((size_t)bid * 256 + tid) * 16;
    u32 o[8];
#pragma unroll
    for (int j = 0; j < 4; j++) {
      float4 f = *(const float4*)&x[base + j * 4];
      o[2 * j] = pk2bf(f.x, f.y);
      o[2 * j + 1] = pk2bf(f.z, f.w);
    }
    *(uint4*)&xb[base] = *(uint4*)&o[0];
    *(uint4*)&xb[base + 8] = *(uint4*)&o[4];
  } else if (bid < 3584) {  // weight transposes [1024][srcN] -> [srcN][1024] bf16
    const float* src;
    u16* dst;
    int gx, t, shift;
    if (bid < 2048) { src = Wq; dst = wqkvT; gx = 32; shift = 5; t = bid - 1024; }
    else if (bid < 2304) { src = Wk; dst = wqkvT + 1024 * 1024; gx = 8; shift = 3; t = bid - 2048; }
    else if (bid < 2560) { src = Wv; dst = wqkvT + 1280 * 1024; gx = 8; shift = 3; t = bid - 2304; }
    else { src = Wo; dst = woT; gx = 32; shift = 5; t = bid - 2560; }
    int srcN = gx * 32;
    int n0 = (t & (gx - 1)) * 32, k0 = (t >> shift) * 32;
    int lx = tid & 31, ly = tid >> 5;
#pragma unroll
    for (int q = 0; q < 4; q++)
      tbuf[ly + 8 * q][lx] = src[(k0 + ly + 8 * q) * srcN + n0 + lx];
    __syncthreads();
#pragma unroll
    for (int q = 0; q < 4; q++)
      dst[(n0 + ly + 8 * q) * 1024 + k0 + lx] = f2bf(tbuf[lx][ly + 8 * q]);
  } else {  // rope tables, 2048*32
    int idx = (bid - 3584) * 256 + tid;
    int i = idx >> 5, j = idx & 31;
    float inv = powf(10000.0f, -(float)j * (1.0f / 32.0f));
    float ang = (float)i * inv;
    rc[idx] = cosf(ang);
    rs[idx] = sinf(ang);
  }
}

// ---------------- GEMM: C[M,N] = A[M,K=1024] * Bt[N,K=1024]^T ----------------
// (R4 verbatim: 64x128 blocks, exact CU fill; MODE 0 grid (12,64)=3/CU,
// MODE 1 grid (8,64)=2/CU. BK=64, XOR-swizzled LDS, double-buffered
// global_load_lds, single barrier per kt.)

template <int MODE>
__global__ __launch_bounds__(256, 3) void gemm_kernel(
    const u16* __restrict__ A, const u16* __restrict__ Bt,
    u16* __restrict__ qo, u16* __restrict__ ko, u16* __restrict__ vo,
    float* __restrict__ fo, const float* __restrict__ rc, const float* __restrict__ rs) {
  constexpr int BM = 64;   // M-tile
  constexpr int TM = 2;    // MFMA tiles per wave in M
  constexpr int WMS = 32;  // wave M-stride
  constexpr int ABSZ = BM * 64;           // one A buffer, u16 elems (4096)
  __shared__ u16 smem[2 * ABSZ + 16384];  // [A0|A1|B0|B1] = 48 KB
  int tid = threadIdx.x;
  int w = tid >> 6, lane = tid & 63, quad = lane >> 4, r = lane & 15;
  int rx = r & 7;
  int wm = w >> 1, wn = w & 1;
  int m0 = blockIdx.y * BM, n0 = blockIdx.x * 128;

  f32x4 acc[TM][4];
#pragma unroll
  for (int a_ = 0; a_ < TM; a_++)
#pragma unroll
    for (int b_ = 0; b_ < 4; b_++) acc[a_][b_] = {0.f, 0.f, 0.f, 0.f};

  // stage kt into buffer buf: A BM rows, B 128 rows x 64 elems, swizzled chunks
  auto stage = [&](int kt, int buf) {
    u16* a_s = smem + buf * ABSZ;
    u16* b_s = smem + 2 * ABSZ + buf * 8192;
#pragma unroll
    for (int it = 0; it < BM / 32; ++it) {
      int cc = it * 256 + tid;
      int row = cc >> 3, p = cc & 7, c = p ^ (row & 7);
      gl2lds16(&A[(size_t)(m0 + row) * 1024 + kt * 64 + c * 8], &a_s[cc * 8]);
    }
#pragma unroll
    for (int it = 0; it < 4; ++it) {
      int cc = it * 256 + tid;
      int row = cc >> 3, p = cc & 7, c = p ^ (row & 7);
      gl2lds16(&Bt[(size_t)(n0 + row) * 1024 + kt * 64 + c * 8], &b_s[cc * 8]);
    }
  };

  stage(0, 0);
  for (int kt = 0; kt < 16; ++kt) {
    int buf = kt & 1;
    __syncthreads();  // single barrier per kt: drains this buf's staging
    if (kt + 1 < 16) stage(kt + 1, buf ^ 1);
    u16* a_s = smem + buf * ABSZ;
    u16* b_s = smem + 2 * ABSZ + buf * 8192;
#pragma unroll
    for (int ks = 0; ks < 2; ks++) {
      int pc = (ks * 4 + quad) ^ rx;
      short8 af[TM], bfr[4];
#pragma unroll
      for (int tm = 0; tm < TM; tm++)
        af[tm] = *(const short8*)&a_s[(wm * WMS + tm * 16 + r) * 64 + pc * 8];
#pragma unroll
      for (int tn = 0; tn < 4; tn++)
        bfr[tn] = *(const short8*)&b_s[(wn * 64 + tn * 16 + r) * 64 + pc * 8];
#pragma unroll
      for (int tm = 0; tm < TM; tm++)
#pragma unroll
        for (int tn = 0; tn < 4; tn++)
          acc[tm][tn] = __builtin_amdgcn_mfma_f32_16x16x32_bf16(af[tm], bfr[tn], acc[tm][tn], 0, 0, 0);
    }
  }

  int nbase = n0 + wn * 64;  // 64-aligned, uniform per wave; region uniform per block
  if constexpr (MODE == 0) {
    if (nbase < 1024) {  // Q + RoPE + QSCALE
      int h = nbase >> 6;
#pragma unroll
      for (int tm = 0; tm < TM; tm++) {
#pragma unroll
        for (int reg = 0; reg < 4; reg++) {
          int m = m0 + wm * WMS + tm * 16 + quad * 4 + reg;
          int b = m >> 11, i = m & 2047;
          size_t base = ((size_t)(b * N_H + h) * N_L + i) * HDIM;
#pragma unroll
          for (int tn = 0; tn < 2; tn++) {
            int dlo = tn * 16 + r;
            float c = rc[i * 32 + dlo], s = rs[i * 32 + dlo];
            float vlo = acc[tm][tn][reg], vhi = acc[tm][tn + 2][reg];
            qo[base + dlo] = f2bf((vlo * c - vhi * s) * QSCALE);
            qo[base + dlo + 32] = f2bf((vhi * c + vlo * s) * QSCALE);
          }
        }
      }
    } else if (nbase < 1280) {  // K + RoPE
      int h = (nbase - 1024) >> 6;
#pragma unroll
      for (int tm = 0; tm < TM; tm++) {
#pragma unroll
        for (int reg = 0; reg < 4; reg++) {
          int m = m0 + wm * WMS + tm * 16 + quad * 4 + reg;
          int b = m >> 11, i = m & 2047;
          size_t base = ((size_t)(b * N_KVH + h) * N_L + i) * HDIM;
#pragma unroll
          for (int tn = 0; tn < 2; tn++) {
            int dlo = tn * 16 + r;
            float c = rc[i * 32 + dlo], s = rs[i * 32 + dlo];
            float vlo = acc[tm][tn][reg], vhi = acc[tm][tn + 2][reg];
            ko[base + dlo] = f2bf(vlo * c - vhi * s);
            ko[base + dlo + 32] = f2bf(vhi * c + vlo * s);
          }
        }
      }
    } else {  // V: transpose bounce reusing staging LDS -> Vt[b][hkv][64][2048]
      __syncthreads();  // all waves done reading staged tiles (block-uniform branch)
      int hkv = (nbase - 1280) >> 6;
      int bb = (m0 + wm * WMS) >> 11;
      int tbase = (m0 + wm * WMS) & 2047;
      u16* myvs = smem + w * 4608;  // [64 d][stride 72], cols 0..31 = 32 tokens/wave
#pragma unroll
      for (int tm = 0; tm < TM; tm++) {
#pragma unroll
        for (int tn = 0; tn < 4; tn++) {
          uint2 pk;
          pk.x = pk2bf(acc[tm][tn][0], acc[tm][tn][1]);
          pk.y = pk2bf(acc[tm][tn][2], acc[tm][tn][3]);
          *(uint2*)&myvs[(tn * 16 + r) * 72 + tm * 16 + quad * 4] = pk;
        }
      }
      __asm__ volatile("s_waitcnt lgkmcnt(0)" ::: "memory");  // wave-local LDS RAW
      u16* vtb = vo + (size_t)((bb * N_KVH + hkv) * 64) * 2048;
#pragma unroll
      for (int q2 = 0; q2 < 4; ++q2) {
        int flat = q2 * 64 + lane;
        int row = flat >> 2, part = flat & 3;  // 64 d-rows x 4 uint4-parts (32 tok)
        uint4 val = *(uint4*)&myvs[row * 72 + part * 8];
        *(uint4*)&vtb[row * 2048 + tbase + part * 8] = val;
      }
    }
  } else {  // MODE 1: fp32 store (quad lanes -> consecutive n, coalesced 64B)
#pragma unroll
    for (int tm = 0; tm < TM; tm++) {
#pragma unroll
      for (int reg = 0; reg < 4; reg++) {
        int m = m0 + wm * WMS + tm * 16 + quad * 4 + reg;
#pragma unroll
        for (int tn = 0; tn < 4; tn++)
          fo[(size_t)m * 1024 + nbase + tn * 16 + r] = acc[tm][tn][reg];
      }
    }
  }
}

// ---------------- flash attention, sliding window, GQA ----------------
// (R4 verbatim revert: V back in LDS. R6's V-from-global regressed 25->57.7us:
// vf loads issued after stage(jt+1) were the newest vmcnt entries, so the wait
// before PV drained the K prefetch too -> pipeline collapse, latency-bound
// profile (MfmaUtil 8%, Occ 28%, HBM 6%). Balanced 24-block grid, setprio,
// XOR-swizzled LDS, double buffer, one barrier per tile.)

__global__ __launch_bounds__(256) void attn_kernel(
    const u16* __restrict__ Q, const u16* __restrict__ K,
    const u16* __restrict__ Vt, u16* __restrict__ O) {
  __shared__ u16 k_s[2][64 * 64];
  __shared__ u16 v_s[2][64 * 64];
  __shared__ u16 pt[4][16 * 64];
  int tid = threadIdx.x, w = tid >> 6, lane = tid & 63, quad = lane >> 4, r = lane & 15;
  int bx = blockIdx.x;
  int h = blockIdx.y, b = blockIdx.z;
  int hk = h >> 2;
  int rx = r & 7;
  u16* mypt = pt[w];

  const u16* kbase = K + (size_t)(b * N_KVH + hk) * N_L * HDIM;
  const u16* vtbase = Vt + (size_t)(b * N_KVH + hk) * HDIM * N_L;

  auto stage = [&](int jt, int buf) {
#pragma unroll
    for (int it = 0; it < 2; ++it) {
      int cc = it * 256 + tid;
      int row = cc >> 3, p = cc & 7, c = p ^ (row & 7);
      gl2lds16(&kbase[(size_t)(jt * 64 + row) * 64 + c * 8], &k_s[buf][cc * 8]);
    }
#pragma unroll
    for (int it = 0; it < 2; ++it) {
      int cc = it * 256 + tid;
      int row = cc >> 3, p = cc & 7, c = p ^ (row & 7);
      gl2lds16(&vtbase[(size_t)row * 2048 + jt * 64 + c * 8], &v_s[buf][cc * 8]);
    }
  };

  int nsub = (bx < 16) ? 1 : 2;
  for (int sp = 0; sp < nsub; ++sp) {
    int qb = (bx < 16) ? (16 + bx) : (sp == 0 ? (bx - 16) : (15 - (bx - 16)));
    if (sp) __syncthreads();  // WAR: all waves done reading bufs of previous subproblem

    int i0 = qb * 64;
    int qw0 = i0 + w * 16;
    int iq = qw0 + r;

    const u16* qptr = Q + (size_t)((b * N_H + h) * N_L + iq) * HDIM;
    short8 qf[2];
    qf[0] = *(const short8*)&qptr[quad * 8];
    qf[1] = *(const short8*)&qptr[32 + quad * 8];

    float l_lane = 0.f;
    f32x4 o_acc[4];
#pragma unroll
    for (int tm = 0; tm < 4; tm++) o_acc[tm] = {0.f, 0.f, 0.f, 0.f};

    int jt0 = (i0 >= WINDOW) ? ((i0 - (WINDOW - 1)) >> 6) : 0;
    int nt = qb - jt0 + 1;

    stage(jt0, 0);

    for (int t = 0; t < nt; ++t) {
      int jt = jt0 + t, j0 = jt << 6, buf = t & 1;
      __syncthreads();  // drains vmcnt: buf's staging complete
      if (t + 1 < nt) stage(jt + 1, buf ^ 1);

      // S^T[j][i]: A = K rows (j), B = Q (i)
      f32x4 s_acc[4];
#pragma unroll
      for (int tm = 0; tm < 4; tm++) s_acc[tm] = {0.f, 0.f, 0.f, 0.f};
      __builtin_amdgcn_s_setprio(1);
#pragma unroll
      for (int ks = 0; ks < 2; ks++) {
        int pc = (ks * 4 + quad) ^ rx;
#pragma unroll
        for (int tm = 0; tm < 4; tm++) {
          short8 kf = *(const short8*)&k_s[buf][(tm * 16 + r) * 64 + pc * 8];
          s_acc[tm] = __builtin_amdgcn_mfma_f32_16x16x32_bf16(kf, qf[ks], s_acc[tm], 0, 0, 0);
        }
      }
      __builtin_amdgcn_s_setprio(0);

      bool interior = (j0 + 63 <= qw0) && (qw0 + 15 - j0 < WINDOW);
      if (!interior) {
#pragma unroll
        for (int tm = 0; tm < 4; tm++) {
#pragma unroll
          for (int reg = 0; reg < 4; reg++) {
            int j = j0 + tm * 16 + quad * 4 + reg;
            bool ok = (j <= iq) && (iq - j < WINDOW);
            if (!ok) s_acc[tm][reg] = -1e30f;  // exp2 -> 0
          }
        }
      }

      // fixed-max softmax: p = exp2(s), in-lane l accumulation, pack to bf16
      float p[4][4];
#pragma unroll
      for (int tm = 0; tm < 4; tm++)
#pragma unroll
        for (int reg = 0; reg < 4; reg++) {
          float e = __builtin_amdgcn_exp2f(s_acc[tm][reg]);
          p[tm][reg] = e;
          l_lane += e;
        }

      // P^T (C-layout) -> pt[i][j] swizzled, wave-local
#pragma unroll
      for (int tm = 0; tm < 4; tm++) {
        uint2 pk;
        pk.x = pk2bf(p[tm][0], p[tm][1]);
        pk.y = pk2bf(p[tm][2], p[tm][3]);
        int c = tm * 2 + (quad >> 1), half = quad & 1;
        int pp = c ^ rx;
        *(uint2*)&mypt[r * 64 + pp * 8 + half * 4] = pk;
      }
      __asm__ volatile("s_waitcnt lgkmcnt(0)" ::: "memory");  // wave-local LDS RAW

      // O^T += Vt * P^T : A = Vt rows (d), B = pt rows (i)
      __builtin_amdgcn_s_setprio(1);
#pragma unroll
      for (int ks = 0; ks < 2; ks++) {
        int pc = (ks * 4 + quad) ^ rx;
        short8 bp = *(const short8*)&mypt[r * 64 + pc * 8];
#pragma unroll
        for (int tm = 0; tm < 4; tm++) {
          short8 av = *(const short8*)&v_s[buf][(tm * 16 + r) * 64 + pc * 8];
          o_acc[tm] = __builtin_amdgcn_mfma_f32_16x16x32_bf16(av, bp, o_acc[tm], 0, 0, 0);
        }
      }
      __builtin_amdgcn_s_setprio(0);
    }

    // epilogue: combine l across quads (once), divide, store
    l_lane += __shfl_xor(l_lane, 16);
    l_lane += __shfl_xor(l_lane, 32);
    float inv = 1.0f / l_lane;
    size_t obase = (size_t)(b * N_L + iq) * 1024 + h * 64;
#pragma unroll
    for (int tm = 0; tm < 4; tm++) {
      uint2 pk;
      pk.x = pk2bf(o_acc[tm][0] * inv, o_acc[tm][1] * inv);
      pk.y = pk2bf(o_acc[tm][2] * inv, o_acc[tm][3] * inv);
      *(uint2*)&O[obase + tm * 16 + quad * 4] = pk;
    }
  }
}

// ---------------- launch ----------------

extern "C" void kernel_launch(void* const* d_in, const int* in_sizes, int n_in,
                              void* d_out, int out_size, void* d_ws, size_t ws_size,
                              hipStream_t stream) {
  const float* x = (const float*)d_in[0];
  const float* Wq = (const float*)d_in[1];
  const float* Wk = (const float*)d_in[2];
  const float* Wv = (const float*)d_in[3];
  const float* Wo = (const float*)d_in[4];
  float* out = (float*)d_out;
  char* ws = (char*)d_ws;

  u16* xb    = (u16*)(ws);                // 8 MB  [4096][1024]
  u16* wqkvT = (u16*)(ws + 0x800000);     // 3 MB  [1536][1024]
  u16* woT   = (u16*)(ws + 0xB00000);     // 2 MB  [1024][1024]
  u16* Qb    = (u16*)(ws + 0xD00000);     // 8 MB  [B][H][L][64] (pre-scaled QSCALE)
  u16* Kb    = (u16*)(ws + 0x1500000);    // 2 MB  [B][KvH][L][64]
  u16* Vtb   = (u16*)(ws + 0x1700000);    // 2 MB  [B][KvH][64][L]  (transposed)
  u16* Ob    = (u16*)(ws + 0x1900000);    // 8 MB  [4096][1024]
  float* rc  = (float*)(ws + 0x2100000);  // 256 KB [2048][32]
  float* rs  = (float*)(ws + 0x2140000);  // 256 KB

  prep_kernel<<<3840, 256, 0, stream>>>(x, Wq, Wk, Wv, Wo, xb, wqkvT, woT, rc, rs);
  // ATTRIBUTION PROBE: both gemms are idempotent (gemm0: xb,wqkvT -> Qb,Kb,Vtb;
  // gemm1: Ob,woT -> out). Run each 3x: Tg0+Tg1 = (dur - 146.8us)/2.
  gemm_kernel<0><<<dim3(12, 64), 256, 0, stream>>>(xb, wqkvT, Qb, Kb, Vtb, nullptr, rc, rs);
  gemm_kernel<0><<<dim3(12, 64), 256, 0, stream>>>(xb, wqkvT, Qb, Kb, Vtb, nullptr, rc, rs);
  gemm_kernel<0><<<dim3(12, 64), 256, 0, stream>>>(xb, wqkvT, Qb, Kb, Vtb, nullptr, rc, rs);
  attn_kernel<<<dim3(24, 16, 2), 256, 0, stream>>>(Qb, Kb, Vtb, Ob);
  gemm_kernel<1><<<dim3(8, 64), 256, 0, stream>>>(Ob, woT, nullptr, nullptr, nullptr, out, nullptr, nullptr);
  gemm_kernel<1><<<dim3(8, 64), 256, 0, stream>>>(Ob, woT, nullptr, nullptr, nullptr, out, nullptr, nullptr);
  gemm_kernel<1><<<dim3(8, 64), 256, 0, stream>>>(Ob, woT, nullptr, nullptr, nullptr, out, nullptr, nullptr);
}

// Round 8
// 169.987 us; speedup vs baseline: 1.2040x; 1.2040x over previous
//
#include <hip/hip_runtime.h>

typedef unsigned short u16;
typedef unsigned int u32;
typedef short short8 __attribute__((ext_vector_type(8)));
typedef float f32x4 __attribute__((ext_vector_type(4)));

#define N_B 2
#define N_L 2048
#define N_D 1024
#define N_H 16
#define N_KVH 4
#define HDIM 64
#define WINDOW 1024

// log2(e) folded into Q so softmax can use exp2 directly
#define QSCALE (0.125f * 1.44269504088896f)

__device__ __forceinline__ u16 f2bf(float f) {
  unsigned u = __builtin_bit_cast(unsigned, f);
  u = u + 0x7fffu + ((u >> 16) & 1u);
  return (u16)(u >> 16);
}

// pack two f32 -> (bf16(hi)<<16)|bf16(lo), round-half-up, one v_perm
__device__ __forceinline__ u32 pk2bf(float lo, float hi) {
  u32 a = __builtin_bit_cast(u32, lo) + 0x8000u;
  u32 b = __builtin_bit_cast(u32, hi) + 0x8000u;
  return __builtin_amdgcn_perm(b, a, 0x07060302u);
}

// async global->LDS, 16B per lane. LDS dest must be wave-uniform base + lane*16.
__device__ __forceinline__ void gl2lds16(const u16* g, u16* l) {
  __builtin_amdgcn_global_load_lds((const __attribute__((address_space(1))) void*)g,
                                   (__attribute__((address_space(3))) void*)l, 16, 0, 0);
}

// ---------------- fused prep: convert x, transpose 4 weights, rope ----------------
// (r6 verbatim known-good version)

__global__ __launch_bounds__(256) void prep_kernel(
    const float* __restrict__ x, const float* __restrict__ Wq, const float* __restrict__ Wk,
    const float* __restrict__ Wv, const float* __restrict__ Wo,
    u16* __restrict__ xb, u16* __restrict__ wqkvT, u16* __restrict__ woT,
    float* __restrict__ rc, float* __restrict__ rs) {
  __shared__ float tbuf[32][33];
  int bid = blockIdx.x, tid = threadIdx.x;
  if (bid < 1024) {  // x fp32 -> bf16, 16 elems/thread
    size_t base = ((size_t)bid * 256 + tid) * 16;
    u32 o[8];
#pragma unroll
    for (int j = 0; j < 4; j++) {
      float4 f = *(const float4*)&x[base + j * 4];
      o[2 * j] = pk2bf(f.x, f.y);
      o[2 * j + 1] = pk2bf(f.z, f.w);
    }
    *(uint4*)&xb[base] = *(uint4*)&o[0];
    *(uint4*)&xb[base + 8] = *(uint4*)&o[4];
  } else if (bid < 3584) {  // weight transposes [1024][srcN] -> [srcN][1024] bf16
    const float* src;
    u16* dst;
    int gx, t, shift;
    if (bid < 2048) { src = Wq; dst = wqkvT; gx = 32; shift = 5; t = bid - 1024; }
    else if (bid < 2304) { src = Wk; dst = wqkvT + 1024 * 1024; gx = 8; shift = 3; t = bid - 2048; }
    else if (bid < 2560) { src = Wv; dst = wqkvT + 1280 * 1024; gx = 8; shift = 3; t = bid - 2304; }
    else { src = Wo; dst = woT; gx = 32; shift = 5; t = bid - 2560; }
    int srcN = gx * 32;
    int n0 = (t & (gx - 1)) * 32, k0 = (t >> shift) * 32;
    int lx = tid & 31, ly = tid >> 5;
#pragma unroll
    for (int q = 0; q < 4; q++)
      tbuf[ly + 8 * q][lx] = src[(k0 + ly + 8 * q) * srcN + n0 + lx];
    __syncthreads();
#pragma unroll
    for (int q = 0; q < 4; q++)
      dst[(n0 + ly + 8 * q) * 1024 + k0 + lx] = f2bf(tbuf[lx][ly + 8 * q]);
  } else {  // rope tables, 2048*32
    int idx = (bid - 3584) * 256 + tid;
    int i = idx >> 5, j = idx & 31;
    float inv = powf(10000.0f, -(float)j * (1.0f / 32.0f));
    float ang = (float)i * inv;
    rc[idx] = cosf(ang);
    rs[idx] = sinf(ang);
  }
}

// ---------------- GEMM: C[M,N] = A[M,K=1024] * Bt[N,K=1024]^T ----------------
// (R4 verbatim: 64x128 blocks, exact CU fill; MODE 0 grid (12,64)=3/CU,
// MODE 1 grid (8,64)=2/CU. BK=64, XOR-swizzled LDS, double-buffered
// global_load_lds, single barrier per kt. R7 probe: Tg0+Tg1 ~= 29us vs ~23.6
// m97-class floor -> leave alone, headroom < risk.)

template <int MODE>
__global__ __launch_bounds__(256, 3) void gemm_kernel(
    const u16* __restrict__ A, const u16* __restrict__ Bt,
    u16* __restrict__ qo, u16* __restrict__ ko, u16* __restrict__ vo,
    float* __restrict__ fo, const float* __restrict__ rc, const float* __restrict__ rs) {
  constexpr int BM = 64;   // M-tile
  constexpr int TM = 2;    // MFMA tiles per wave in M
  constexpr int WMS = 32;  // wave M-stride
  constexpr int ABSZ = BM * 64;           // one A buffer, u16 elems (4096)
  __shared__ u16 smem[2 * ABSZ + 16384];  // [A0|A1|B0|B1] = 48 KB
  int tid = threadIdx.x;
  int w = tid >> 6, lane = tid & 63, quad = lane >> 4, r = lane & 15;
  int rx = r & 7;
  int wm = w >> 1, wn = w & 1;
  int m0 = blockIdx.y * BM, n0 = blockIdx.x * 128;

  f32x4 acc[TM][4];
#pragma unroll
  for (int a_ = 0; a_ < TM; a_++)
#pragma unroll
    for (int b_ = 0; b_ < 4; b_++) acc[a_][b_] = {0.f, 0.f, 0.f, 0.f};

  // stage kt into buffer buf: A BM rows, B 128 rows x 64 elems, swizzled chunks
  auto stage = [&](int kt, int buf) {
    u16* a_s = smem + buf * ABSZ;
    u16* b_s = smem + 2 * ABSZ + buf * 8192;
#pragma unroll
    for (int it = 0; it < BM / 32; ++it) {
      int cc = it * 256 + tid;
      int row = cc >> 3, p = cc & 7, c = p ^ (row & 7);
      gl2lds16(&A[(size_t)(m0 + row) * 1024 + kt * 64 + c * 8], &a_s[cc * 8]);
    }
#pragma unroll
    for (int it = 0; it < 4; ++it) {
      int cc = it * 256 + tid;
      int row = cc >> 3, p = cc & 7, c = p ^ (row & 7);
      gl2lds16(&Bt[(size_t)(n0 + row) * 1024 + kt * 64 + c * 8], &b_s[cc * 8]);
    }
  };

  stage(0, 0);
  for (int kt = 0; kt < 16; ++kt) {
    int buf = kt & 1;
    __syncthreads();  // single barrier per kt: drains this buf's staging
    if (kt + 1 < 16) stage(kt + 1, buf ^ 1);
    u16* a_s = smem + buf * ABSZ;
    u16* b_s = smem + 2 * ABSZ + buf * 8192;
#pragma unroll
    for (int ks = 0; ks < 2; ks++) {
      int pc = (ks * 4 + quad) ^ rx;
      short8 af[TM], bfr[4];
#pragma unroll
      for (int tm = 0; tm < TM; tm++)
        af[tm] = *(const short8*)&a_s[(wm * WMS + tm * 16 + r) * 64 + pc * 8];
#pragma unroll
      for (int tn = 0; tn < 4; tn++)
        bfr[tn] = *(const short8*)&b_s[(wn * 64 + tn * 16 + r) * 64 + pc * 8];
#pragma unroll
      for (int tm = 0; tm < TM; tm++)
#pragma unroll
        for (int tn = 0; tn < 4; tn++)
          acc[tm][tn] = __builtin_amdgcn_mfma_f32_16x16x32_bf16(af[tm], bfr[tn], acc[tm][tn], 0, 0, 0);
    }
  }

  int nbase = n0 + wn * 64;  // 64-aligned, uniform per wave; region uniform per block
  if constexpr (MODE == 0) {
    if (nbase < 1024) {  // Q + RoPE + QSCALE
      int h = nbase >> 6;
#pragma unroll
      for (int tm = 0; tm < TM; tm++) {
#pragma unroll
        for (int reg = 0; reg < 4; reg++) {
          int m = m0 + wm * WMS + tm * 16 + quad * 4 + reg;
          int b = m >> 11, i = m & 2047;
          size_t base = ((size_t)(b * N_H + h) * N_L + i) * HDIM;
#pragma unroll
          for (int tn = 0; tn < 2; tn++) {
            int dlo = tn * 16 + r;
            float c = rc[i * 32 + dlo], s = rs[i * 32 + dlo];
            float vlo = acc[tm][tn][reg], vhi = acc[tm][tn + 2][reg];
            qo[base + dlo] = f2bf((vlo * c - vhi * s) * QSCALE);
            qo[base + dlo + 32] = f2bf((vhi * c + vlo * s) * QSCALE);
          }
        }
      }
    } else if (nbase < 1280) {  // K + RoPE
      int h = (nbase - 1024) >> 6;
#pragma unroll
      for (int tm = 0; tm < TM; tm++) {
#pragma unroll
        for (int reg = 0; reg < 4; reg++) {
          int m = m0 + wm * WMS + tm * 16 + quad * 4 + reg;
          int b = m >> 11, i = m & 2047;
          size_t base = ((size_t)(b * N_KVH + h) * N_L + i) * HDIM;
#pragma unroll
          for (int tn = 0; tn < 2; tn++) {
            int dlo = tn * 16 + r;
            float c = rc[i * 32 + dlo], s = rs[i * 32 + dlo];
            float vlo = acc[tm][tn][reg], vhi = acc[tm][tn + 2][reg];
            ko[base + dlo] = f2bf(vlo * c - vhi * s);
            ko[base + dlo + 32] = f2bf(vhi * c + vlo * s);
          }
        }
      }
    } else {  // V: transpose bounce reusing staging LDS -> Vt[b][hkv][64][2048]
      __syncthreads();  // all waves done reading staged tiles (block-uniform branch)
      int hkv = (nbase - 1280) >> 6;
      int bb = (m0 + wm * WMS) >> 11;
      int tbase = (m0 + wm * WMS) & 2047;
      u16* myvs = smem + w * 4608;  // [64 d][stride 72], cols 0..31 = 32 tokens/wave
#pragma unroll
      for (int tm = 0; tm < TM; tm++) {
#pragma unroll
        for (int tn = 0; tn < 4; tn++) {
          uint2 pk;
          pk.x = pk2bf(acc[tm][tn][0], acc[tm][tn][1]);
          pk.y = pk2bf(acc[tm][tn][2], acc[tm][tn][3]);
          *(uint2*)&myvs[(tn * 16 + r) * 72 + tm * 16 + quad * 4] = pk;
        }
      }
      __asm__ volatile("s_waitcnt lgkmcnt(0)" ::: "memory");  // wave-local LDS RAW
      u16* vtb = vo + (size_t)((bb * N_KVH + hkv) * 64) * 2048;
#pragma unroll
      for (int q2 = 0; q2 < 4; ++q2) {
        int flat = q2 * 64 + lane;
        int row = flat >> 2, part = flat & 3;  // 64 d-rows x 4 uint4-parts (32 tok)
        uint4 val = *(uint4*)&myvs[row * 72 + part * 8];
        *(uint4*)&vtb[row * 2048 + tbase + part * 8] = val;
      }
    }
  } else {  // MODE 1: fp32 store (quad lanes -> consecutive n, coalesced 64B)
#pragma unroll
    for (int tm = 0; tm < TM; tm++) {
#pragma unroll
      for (int reg = 0; reg < 4; reg++) {
        int m = m0 + wm * WMS + tm * 16 + quad * 4 + reg;
#pragma unroll
        for (int tn = 0; tn < 4; tn++)
          fo[(size_t)m * 1024 + nbase + tn * 16 + r] = acc[tm][tn][reg];
      }
    }
  }
}

// ---------------- flash attention, sliding window, GQA ----------------
// Balanced 24-block grid, setprio, XOR-swizzled K LDS, double-buffered K
// staging, one barrier per tile.
// ROUND 8: V-from-global RETRY with the vmcnt ordering fixed. R6 regressed
// because vf loads were issued AFTER stage(t+1): vmcnt waits oldest-first, so
// the register-dependency wait on vf before PV drained the K prefetch too ->
// full latency exposure every tile (MfmaUtil 8%). Fix: issue the 8 vf loads
// IMMEDIATELY after the barrier, BEFORE stage(t+1). The PV wait then leaves
// the 2 younger K-staging loads in flight (vmcnt(2)), preserving the pipeline,
// and vf's L2 latency hides under QK^T + softmax. Gains: LDS reads/wave-tile
// 18 -> 10, barrier drain halves (2 gl2lds not 4), LDS 40 -> 24 KB.

__global__ __launch_bounds__(256) void attn_kernel(
    const u16* __restrict__ Q, const u16* __restrict__ K,
    const u16* __restrict__ Vt, u16* __restrict__ O) {
  __shared__ u16 k_s[2][64 * 64];
  __shared__ u16 pt[4][16 * 64];
  int tid = threadIdx.x, w = tid >> 6, lane = tid & 63, quad = lane >> 4, r = lane & 15;
  int bx = blockIdx.x;
  int h = blockIdx.y, b = blockIdx.z;
  int hk = h >> 2;
  int rx = r & 7;
  u16* mypt = pt[w];

  const u16* kbase = K + (size_t)(b * N_KVH + hk) * N_L * HDIM;
  const u16* vtbase = Vt + (size_t)(b * N_KVH + hk) * HDIM * N_L;
  // per-lane V fragment base: row r (within each 16-row d-tile), col chunk quad*8
  const u16* vlane = vtbase + (size_t)r * 2048 + quad * 8;

  auto stage = [&](int jt, int buf) {
#pragma unroll
    for (int it = 0; it < 2; ++it) {
      int cc = it * 256 + tid;
      int row = cc >> 3, p = cc & 7, c = p ^ (row & 7);
      gl2lds16(&kbase[(size_t)(jt * 64 + row) * 64 + c * 8], &k_s[buf][cc * 8]);
    }
  };

  int nsub = (bx < 16) ? 1 : 2;
  for (int sp = 0; sp < nsub; ++sp) {
    int qb = (bx < 16) ? (16 + bx) : (sp == 0 ? (bx - 16) : (15 - (bx - 16)));
    if (sp) __syncthreads();  // WAR: all waves done reading bufs of previous subproblem

    int i0 = qb * 64;
    int qw0 = i0 + w * 16;
    int iq = qw0 + r;

    const u16* qptr = Q + (size_t)((b * N_H + h) * N_L + iq) * HDIM;
    short8 qf[2];
    qf[0] = *(const short8*)&qptr[quad * 8];
    qf[1] = *(const short8*)&qptr[32 + quad * 8];

    float l_lane = 0.f;
    f32x4 o_acc[4];
#pragma unroll
    for (int tm = 0; tm < 4; tm++) o_acc[tm] = {0.f, 0.f, 0.f, 0.f};

    int jt0 = (i0 >= WINDOW) ? ((i0 - (WINDOW - 1)) >> 6) : 0;
    int nt = qb - jt0 + 1;

    stage(jt0, 0);

    for (int t = 0; t < nt; ++t) {
      int jt = jt0 + t, j0 = jt << 6, buf = t & 1;
      __syncthreads();  // drains vmcnt: buf's K staging complete

      // V fragments for THIS tile: global->VGPR in MFMA A-fragment layout.
      // Issued FIRST (before stage) so the pre-PV dependency wait leaves the
      // younger K prefetch in flight (vmcnt ordering, oldest-first).
      short8 vf[4][2];
#pragma unroll
      for (int tm = 0; tm < 4; tm++)
#pragma unroll
        for (int ks = 0; ks < 2; ks++)
          vf[tm][ks] = *(const short8*)&vlane[(size_t)tm * 16 * 2048 + j0 + ks * 32];

      if (t + 1 < nt) stage(jt + 1, buf ^ 1);

      // S^T[j][i]: A = K rows (j), B = Q (i)
      f32x4 s_acc[4];
#pragma unroll
      for (int tm = 0; tm < 4; tm++) s_acc[tm] = {0.f, 0.f, 0.f, 0.f};
      __builtin_amdgcn_s_setprio(1);
#pragma unroll
      for (int ks = 0; ks < 2; ks++) {
        int pc = (ks * 4 + quad) ^ rx;
#pragma unroll
        for (int tm = 0; tm < 4; tm++) {
          short8 kf = *(const short8*)&k_s[buf][(tm * 16 + r) * 64 + pc * 8];
          s_acc[tm] = __builtin_amdgcn_mfma_f32_16x16x32_bf16(kf, qf[ks], s_acc[tm], 0, 0, 0);
        }
      }
      __builtin_amdgcn_s_setprio(0);

      bool interior = (j0 + 63 <= qw0) && (qw0 + 15 - j0 < WINDOW);
      if (!interior) {
#pragma unroll
        for (int tm = 0; tm < 4; tm++) {
#pragma unroll
          for (int reg = 0; reg < 4; reg++) {
            int j = j0 + tm * 16 + quad * 4 + reg;
            bool ok = (j <= iq) && (iq - j < WINDOW);
            if (!ok) s_acc[tm][reg] = -1e30f;  // exp2 -> 0
          }
        }
      }

      // fixed-max softmax: p = exp2(s), in-lane l accumulation, pack to bf16
      float p[4][4];
#pragma unroll
      for (int tm = 0; tm < 4; tm++)
#pragma unroll
        for (int reg = 0; reg < 4; reg++) {
          float e = __builtin_amdgcn_exp2f(s_acc[tm][reg]);
          p[tm][reg] = e;
          l_lane += e;
        }

      // P^T (C-layout) -> pt[i][j] swizzled, wave-local
#pragma unroll
      for (int tm = 0; tm < 4; tm++) {
        uint2 pk;
        pk.x = pk2bf(p[tm][0], p[tm][1]);
        pk.y = pk2bf(p[tm][2], p[tm][3]);
        int c = tm * 2 + (quad >> 1), half = quad & 1;
        int pp = c ^ rx;
        *(uint2*)&mypt[r * 64 + pp * 8 + half * 4] = pk;
      }
      __asm__ volatile("s_waitcnt lgkmcnt(0)" ::: "memory");  // wave-local LDS RAW

      // O^T += Vt * P^T : A = Vt rows (d, in regs), B = pt rows (i)
      __builtin_amdgcn_s_setprio(1);
#pragma unroll
      for (int ks = 0; ks < 2; ks++) {
        int pc = (ks * 4 + quad) ^ rx;
        short8 bp = *(const short8*)&mypt[r * 64 + pc * 8];
#pragma unroll
        for (int tm = 0; tm < 4; tm++)
          o_acc[tm] = __builtin_amdgcn_mfma_f32_16x16x32_bf16(vf[tm][ks], bp, o_acc[tm], 0, 0, 0);
      }
      __builtin_amdgcn_s_setprio(0);
    }

    // epilogue: combine l across quads (once), divide, store
    l_lane += __shfl_xor(l_lane, 16);
    l_lane += __shfl_xor(l_lane, 32);
    float inv = 1.0f / l_lane;
    size_t obase = (size_t)(b * N_L + iq) * 1024 + h * 64;
#pragma unroll
    for (int tm = 0; tm < 4; tm++) {
      uint2 pk;
      pk.x = pk2bf(o_acc[tm][0] * inv, o_acc[tm][1] * inv);
      pk.y = pk2bf(o_acc[tm][2] * inv, o_acc[tm][3] * inv);
      *(uint2*)&O[obase + tm * 16 + quad * 4] = pk;
    }
  }
}

// ---------------- launch ----------------

extern "C" void kernel_launch(void* const* d_in, const int* in_sizes, int n_in,
                              void* d_out, int out_size, void* d_ws, size_t ws_size,
                              hipStream_t stream) {
  const float* x = (const float*)d_in[0];
  const float* Wq = (const float*)d_in[1];
  const float* Wk = (const float*)d_in[2];
  const float* Wv = (const float*)d_in[3];
  const float* Wo = (const float*)d_in[4];
  float* out = (float*)d_out;
  char* ws = (char*)d_ws;

  u16* xb    = (u16*)(ws);                // 8 MB  [4096][1024]
  u16* wqkvT = (u16*)(ws + 0x800000);     // 3 MB  [1536][1024]
  u16* woT   = (u16*)(ws + 0xB00000);     // 2 MB  [1024][1024]
  u16* Qb    = (u16*)(ws + 0xD00000);     // 8 MB  [B][H][L][64] (pre-scaled QSCALE)
  u16* Kb    = (u16*)(ws + 0x1500000);    // 2 MB  [B][KvH][L][64]
  u16* Vtb   = (u16*)(ws + 0x1700000);    // 2 MB  [B][KvH][64][L]  (transposed)
  u16* Ob    = (u16*)(ws + 0x1900000);    // 8 MB  [4096][1024]
  float* rc  = (float*)(ws + 0x2100000);  // 256 KB [2048][32]
  float* rs  = (float*)(ws + 0x2140000);  // 256 KB

  prep_kernel<<<3840, 256, 0, stream>>>(x, Wq, Wk, Wv, Wo, xb, wqkvT, woT, rc, rs);
  gemm_kernel<0><<<dim3(12, 64), 256, 0, stream>>>(xb, wqkvT, Qb, Kb, Vtb, nullptr, rc, rs);
  attn_kernel<<<dim3(24, 16, 2), 256, 0, stream>>>(Qb, Kb, Vtb, Ob);
  gemm_kernel<1><<<dim3(8, 64), 256, 0, stream>>>(Ob, woT, nullptr, nullptr, nullptr, out, nullptr, nullptr);
}

// Round 9
// 145.419 us; speedup vs baseline: 1.4074x; 1.1689x over previous
//
#include <hip/hip_runtime.h>

typedef unsigned short u16;
typedef unsigned int u32;
typedef short short8 __attribute__((ext_vector_type(8)));
typedef float f32x4 __attribute__((ext_vector_type(4)));

#define N_B 2
#define N_L 2048
#define N_D 1024
#define N_H 16
#define N_KVH 4
#define HDIM 64
#define WINDOW 1024

// log2(e) folded into Q so softmax can use exp2 directly
#define QSCALE (0.125f * 1.44269504088896f)

__device__ __forceinline__ u16 f2bf(float f) {
  unsigned u = __builtin_bit_cast(unsigned, f);
  u = u + 0x7fffu + ((u >> 16) & 1u);
  return (u16)(u >> 16);
}

// pack two f32 -> (bf16(hi)<<16)|bf16(lo), round-half-up, one v_perm
__device__ __forceinline__ u32 pk2bf(float lo, float hi) {
  u32 a = __builtin_bit_cast(u32, lo) + 0x8000u;
  u32 b = __builtin_bit_cast(u32, hi) + 0x8000u;
  return __builtin_amdgcn_perm(b, a, 0x07060302u);
}

// async global->LDS, 16B per lane. LDS dest must be wave-uniform base + lane*16.
__device__ __forceinline__ void gl2lds16(const u16* g, u16* l) {
  __builtin_amdgcn_global_load_lds((const __attribute__((address_space(1))) void*)g,
                                   (__attribute__((address_space(3))) void*)l, 16, 0, 0);
}

// ---------------- fused prep: convert x, transpose 4 weights, rope ----------------
// (r6 verbatim known-good version)

__global__ __launch_bounds__(256) void prep_kernel(
    const float* __restrict__ x, const float* __restrict__ Wq, const float* __restrict__ Wk,
    const float* __restrict__ Wv, const float* __restrict__ Wo,
    u16* __restrict__ xb, u16* __restrict__ wqkvT, u16* __restrict__ woT,
    float* __restrict__ rc, float* __restrict__ rs) {
  __shared__ float tbuf[32][33];
  int bid = blockIdx.x, tid = threadIdx.x;
  if (bid < 1024) {  // x fp32 -> bf16, 16 elems/thread
    size_t base = ((size_t)bid * 256 + tid) * 16;
    u32 o[8];
#pragma unroll
    for (int j = 0; j < 4; j++) {
      float4 f = *(const float4*)&x[base + j * 4];
      o[2 * j] = pk2bf(f.x, f.y);
      o[2 * j + 1] = pk2bf(f.z, f.w);
    }
    *(uint4*)&xb[base] = *(uint4*)&o[0];
    *(uint4*)&xb[base + 8] = *(uint4*)&o[4];
  } else if (bid < 3584) {  // weight transposes [1024][srcN] -> [srcN][1024] bf16
    const float* src;
    u16* dst;
    int gx, t, shift;
    if (bid < 2048) { src = Wq; dst = wqkvT; gx = 32; shift = 5; t = bid - 1024; }
    else if (bid < 2304) { src = Wk; dst = wqkvT + 1024 * 1024; gx = 8; shift = 3; t = bid - 2048; }
    else if (bid < 2560) { src = Wv; dst = wqkvT + 1280 * 1024; gx = 8; shift = 3; t = bid - 2304; }
    else { src = Wo; dst = woT; gx = 32; shift = 5; t = bid - 2560; }
    int srcN = gx * 32;
    int n0 = (t & (gx - 1)) * 32, k0 = (t >> shift) * 32;
    int lx = tid & 31, ly = tid >> 5;
#pragma unroll
    for (int q = 0; q < 4; q++)
      tbuf[ly + 8 * q][lx] = src[(k0 + ly + 8 * q) * srcN + n0 + lx];
    __syncthreads();
#pragma unroll
    for (int q = 0; q < 4; q++)
      dst[(n0 + ly + 8 * q) * 1024 + k0 + lx] = f2bf(tbuf[lx][ly + 8 * q]);
  } else {  // rope tables, 2048*32
    int idx = (bid - 3584) * 256 + tid;
    int i = idx >> 5, j = idx & 31;
    float inv = powf(10000.0f, -(float)j * (1.0f / 32.0f));
    float ang = (float)i * inv;
    rc[idx] = cosf(ang);
    rs[idx] = sinf(ang);
  }
}

// ---------------- GEMM: C[M,N] = A[M,K=1024] * Bt[N,K=1024]^T ----------------
// MODE 0: 128x128 block (grid 12x32 = 384 blocks), 4 waves 2x2 each 64x64 ->
//         0.5 ds_read/MFMA. qkv projection; RoPE epilogue (Q scaled by QSCALE);
//         V stored transposed as Vt[b][hkv][64][2048].
// MODE 1: 64x128 block (grid 8x64 = 512 blocks = exactly 2/CU resident, 48KB
//         LDS). At 128x128 gemm1 had 256 blocks = 1/CU: the single
//         barrier-per-kt pipeline relies on a co-resident block to absorb the
//         vmcnt-drain stall (m114).
// Both: BK=64, XOR-swizzled LDS, double-buffered global_load_lds, SINGLE
// barrier per kt (prefetch kt+1 issued right after the barrier stays in flight
// across the whole kt compute).
// Session note (R5/R7 probes): Tg0+Tg1 ~= 29us vs ~24us m97-class floor;
// R4's exact-fill 64x128 MODE 0 variant measured the same within noise.
// This is the best-measured configuration (R2, 145.7us).

template <int MODE>
__global__ __launch_bounds__(256, 2) void gemm_kernel(
    const u16* __restrict__ A, const u16* __restrict__ Bt,
    u16* __restrict__ qo, u16* __restrict__ ko, u16* __restrict__ vo,
    float* __restrict__ fo, const float* __restrict__ rc, const float* __restrict__ rs) {
  constexpr int BM = MODE ? 64 : 128;   // M-tile
  constexpr int TM = MODE ? 2 : 4;      // MFMA tiles per wave in M
  constexpr int WMS = MODE ? 32 : 64;   // wave M-stride
  constexpr int ABSZ = BM * 64;         // one A buffer, u16 elems
  __shared__ u16 smem[2 * ABSZ + 16384];  // [A0|A1|B0|B1]
  int tid = threadIdx.x;
  int w = tid >> 6, lane = tid & 63, quad = lane >> 4, r = lane & 15;
  int rx = r & 7;
  int wm = w >> 1, wn = w & 1;
  int m0 = blockIdx.y * BM, n0 = blockIdx.x * 128;

  f32x4 acc[TM][4];
#pragma unroll
  for (int a_ = 0; a_ < TM; a_++)
#pragma unroll
    for (int b_ = 0; b_ < 4; b_++) acc[a_][b_] = {0.f, 0.f, 0.f, 0.f};

  // stage kt into buffer buf: A BM rows, B 128 rows x 64 elems, swizzled chunks
  auto stage = [&](int kt, int buf) {
    u16* a_s = smem + buf * ABSZ;
    u16* b_s = smem + 2 * ABSZ + buf * 8192;
#pragma unroll
    for (int it = 0; it < BM / 32; ++it) {
      int cc = it * 256 + tid;
      int row = cc >> 3, p = cc & 7, c = p ^ (row & 7);
      gl2lds16(&A[(size_t)(m0 + row) * 1024 + kt * 64 + c * 8], &a_s[cc * 8]);
    }
#pragma unroll
    for (int it = 0; it < 4; ++it) {
      int cc = it * 256 + tid;
      int row = cc >> 3, p = cc & 7, c = p ^ (row & 7);
      gl2lds16(&Bt[(size_t)(n0 + row) * 1024 + kt * 64 + c * 8], &b_s[cc * 8]);
    }
  };

  stage(0, 0);
  for (int kt = 0; kt < 16; ++kt) {
    int buf = kt & 1;
    __syncthreads();  // single barrier per kt: drains this buf's staging
    if (kt + 1 < 16) stage(kt + 1, buf ^ 1);
    u16* a_s = smem + buf * ABSZ;
    u16* b_s = smem + 2 * ABSZ + buf * 8192;
#pragma unroll
    for (int ks = 0; ks < 2; ks++) {
      int pc = (ks * 4 + quad) ^ rx;
      short8 af[TM], bfr[4];
#pragma unroll
      for (int tm = 0; tm < TM; tm++)
        af[tm] = *(const short8*)&a_s[(wm * WMS + tm * 16 + r) * 64 + pc * 8];
#pragma unroll
      for (int tn = 0; tn < 4; tn++)
        bfr[tn] = *(const short8*)&b_s[(wn * 64 + tn * 16 + r) * 64 + pc * 8];
#pragma unroll
      for (int tm = 0; tm < TM; tm++)
#pragma unroll
        for (int tn = 0; tn < 4; tn++)
          acc[tm][tn] = __builtin_amdgcn_mfma_f32_16x16x32_bf16(af[tm], bfr[tn], acc[tm][tn], 0, 0, 0);
    }
  }

  int nbase = n0 + wn * 64;  // 64-aligned, uniform per wave
  if constexpr (MODE == 0) {
    if (nbase < 1024) {  // Q + RoPE + QSCALE
      int h = nbase >> 6;
#pragma unroll
      for (int tm = 0; tm < 4; tm++) {
#pragma unroll
        for (int reg = 0; reg < 4; reg++) {
          int m = m0 + wm * 64 + tm * 16 + quad * 4 + reg;
          int b = m >> 11, i = m & 2047;
          size_t base = ((size_t)(b * N_H + h) * N_L + i) * HDIM;
#pragma unroll
          for (int tn = 0; tn < 2; tn++) {
            int dlo = tn * 16 + r;
            float c = rc[i * 32 + dlo], s = rs[i * 32 + dlo];
            float vlo = acc[tm][tn][reg], vhi = acc[tm][tn + 2][reg];
            qo[base + dlo] = f2bf((vlo * c - vhi * s) * QSCALE);
            qo[base + dlo + 32] = f2bf((vhi * c + vlo * s) * QSCALE);
          }
        }
      }
    } else if (nbase < 1280) {  // K + RoPE
      int h = (nbase - 1024) >> 6;
#pragma unroll
      for (int tm = 0; tm < 4; tm++) {
#pragma unroll
        for (int reg = 0; reg < 4; reg++) {
          int m = m0 + wm * 64 + tm * 16 + quad * 4 + reg;
          int b = m >> 11, i = m & 2047;
          size_t base = ((size_t)(b * N_KVH + h) * N_L + i) * HDIM;
#pragma unroll
          for (int tn = 0; tn < 2; tn++) {
            int dlo = tn * 16 + r;
            float c = rc[i * 32 + dlo], s = rs[i * 32 + dlo];
            float vlo = acc[tm][tn][reg], vhi = acc[tm][tn + 2][reg];
            ko[base + dlo] = f2bf(vlo * c - vhi * s);
            ko[base + dlo + 32] = f2bf(vhi * c + vlo * s);
          }
        }
      }
    } else {  // V: transpose bounce reusing staging LDS -> Vt[b][hkv][64][2048]
      __syncthreads();  // all waves done reading staged tiles
      int hkv = (nbase - 1280) >> 6;
      int bb = (m0 + wm * 64) >> 11;
      int tbase = (m0 + wm * 64) & 2047;
      u16* myvs = smem + w * 4608;  // [64 d][64 tok] stride 72, 9216 B per wave
#pragma unroll
      for (int tm = 0; tm < 4; tm++) {
#pragma unroll
        for (int tn = 0; tn < 4; tn++) {
          uint2 pk;
          pk.x = pk2bf(acc[tm][tn][0], acc[tm][tn][1]);
          pk.y = pk2bf(acc[tm][tn][2], acc[tm][tn][3]);
          *(uint2*)&myvs[(tn * 16 + r) * 72 + tm * 16 + quad * 4] = pk;
        }
      }
      __asm__ volatile("s_waitcnt lgkmcnt(0)" ::: "memory");  // wave-local LDS RAW
      u16* vtb = vo + (size_t)((bb * N_KVH + hkv) * 64) * 2048;
#pragma unroll
      for (int q2 = 0; q2 < 8; ++q2) {
        int flat = q2 * 64 + lane;
        int row = flat >> 3, part = flat & 7;
        uint4 val = *(uint4*)&myvs[row * 72 + part * 8];
        *(uint4*)&vtb[row * 2048 + tbase + part * 8] = val;
      }
    }
  } else {  // MODE 1: fp32 store (quad lanes -> consecutive n, coalesced 64B)
#pragma unroll
    for (int tm = 0; tm < TM; tm++) {
#pragma unroll
      for (int reg = 0; reg < 4; reg++) {
        int m = m0 + wm * WMS + tm * 16 + quad * 4 + reg;
#pragma unroll
        for (int tn = 0; tn < 4; tn++)
          fo[(size_t)m * 1024 + nbase + tn * 16 + r] = acc[tm][tn][reg];
      }
    }
  }
}

// ---------------- flash attention, sliding window, GQA ----------------
// S^T = K*Q^T (key-reduction in-lane), O^T = Vt*P^T.
// Fixed-max softmax: p = exp2(s), l accumulated in-lane, no cross-lane in loop.
// XOR-swizzled LDS, double-buffered K/V staging via global_load_lds, one
// barrier per tile, setprio around MFMA clusters (T5, m191).
// Session findings (R5-R8 probes): T_attn ~= 25us here. V-from-global
// (R6/R8) regresses 2.4x: each of 4 waves loads the full 8KB V tile into
// registers -> 4x L2 traffic at 64B granularity, L2-BW/latency bound
// (MfmaUtil 8%). LDS staging shares the tile across waves -- keep it.
// Wave-widening (R1) and grid balancing (R3/R4) both neutral. Bank conflicts
// measured negligible (~3K cy/CU/dispatch).

__global__ __launch_bounds__(256) void attn_kernel(
    const u16* __restrict__ Q, const u16* __restrict__ K,
    const u16* __restrict__ Vt, u16* __restrict__ O) {
  __shared__ u16 k_s[2][64 * 64];
  __shared__ u16 v_s[2][64 * 64];
  __shared__ u16 pt[4][16 * 64];
  int tid = threadIdx.x, w = tid >> 6, lane = tid & 63, quad = lane >> 4, r = lane & 15;
  int qb = 31 - blockIdx.x;  // long blocks first
  int h = blockIdx.y, b = blockIdx.z;
  int i0 = qb * 64;
  int hk = h >> 2;
  int qw0 = i0 + w * 16;
  int iq = qw0 + r;

  const u16* qptr = Q + (size_t)((b * N_H + h) * N_L + iq) * HDIM;
  short8 qf[2];
  qf[0] = *(const short8*)&qptr[quad * 8];
  qf[1] = *(const short8*)&qptr[32 + quad * 8];

  const u16* kbase = K + (size_t)(b * N_KVH + hk) * N_L * HDIM;
  const u16* vtbase = Vt + (size_t)(b * N_KVH + hk) * HDIM * N_L;

  auto stage = [&](int jt, int buf) {
#pragma unroll
    for (int it = 0; it < 2; ++it) {
      int cc = it * 256 + tid;
      int row = cc >> 3, p = cc & 7, c = p ^ (row & 7);
      gl2lds16(&kbase[(size_t)(jt * 64 + row) * 64 + c * 8], &k_s[buf][cc * 8]);
    }
#pragma unroll
    for (int it = 0; it < 2; ++it) {
      int cc = it * 256 + tid;
      int row = cc >> 3, p = cc & 7, c = p ^ (row & 7);
      gl2lds16(&vtbase[(size_t)row * 2048 + jt * 64 + c * 8], &v_s[buf][cc * 8]);
    }
  };

  float l_lane = 0.f;
  f32x4 o_acc[4];
#pragma unroll
  for (int tm = 0; tm < 4; tm++) o_acc[tm] = {0.f, 0.f, 0.f, 0.f};

  int jt0 = (i0 >= WINDOW) ? ((i0 - (WINDOW - 1)) >> 6) : 0;
  int nt = qb - jt0 + 1;
  u16* mypt = pt[w];
  int rx = r & 7;

  stage(jt0, 0);

  for (int t = 0; t < nt; ++t) {
    int jt = jt0 + t, j0 = jt << 6, buf = t & 1;
    __syncthreads();  // drains vmcnt: buf's staging complete
    if (t + 1 < nt) stage(jt + 1, buf ^ 1);

    // S^T[j][i]: A = K rows (j), B = Q (i)
    f32x4 s_acc[4];
#pragma unroll
    for (int tm = 0; tm < 4; tm++) s_acc[tm] = {0.f, 0.f, 0.f, 0.f};
    __builtin_amdgcn_s_setprio(1);
#pragma unroll
    for (int ks = 0; ks < 2; ks++) {
      int pc = (ks * 4 + quad) ^ rx;
#pragma unroll
      for (int tm = 0; tm < 4; tm++) {
        short8 kf = *(const short8*)&k_s[buf][(tm * 16 + r) * 64 + pc * 8];
        s_acc[tm] = __builtin_amdgcn_mfma_f32_16x16x32_bf16(kf, qf[ks], s_acc[tm], 0, 0, 0);
      }
    }
    __builtin_amdgcn_s_setprio(0);

    bool interior = (j0 + 63 <= qw0) && (qw0 + 15 - j0 < WINDOW);
    if (!interior) {
#pragma unroll
      for (int tm = 0; tm < 4; tm++) {
#pragma unroll
        for (int reg = 0; reg < 4; reg++) {
          int j = j0 + tm * 16 + quad * 4 + reg;
          bool ok = (j <= iq) && (iq - j < WINDOW);
          if (!ok) s_acc[tm][reg] = -1e30f;  // exp2 -> 0
        }
      }
    }

    // fixed-max softmax: p = exp2(s), in-lane l accumulation, pack to bf16
    float p[4][4];
#pragma unroll
    for (int tm = 0; tm < 4; tm++)
#pragma unroll
      for (int reg = 0; reg < 4; reg++) {
        float e = __builtin_amdgcn_exp2f(s_acc[tm][reg]);
        p[tm][reg] = e;
        l_lane += e;
      }

    // P^T (C-layout) -> pt[i][j] swizzled, wave-local
#pragma unroll
    for (int tm = 0; tm < 4; tm++) {
      uint2 pk;
      pk.x = pk2bf(p[tm][0], p[tm][1]);
      pk.y = pk2bf(p[tm][2], p[tm][3]);
      int c = tm * 2 + (quad >> 1), half = quad & 1;
      int pp = c ^ rx;
      *(uint2*)&mypt[r * 64 + pp * 8 + half * 4] = pk;
    }
    __asm__ volatile("s_waitcnt lgkmcnt(0)" ::: "memory");  // wave-local LDS RAW

    // O^T += Vt * P^T : A = Vt rows (d), B = pt rows (i)
    __builtin_amdgcn_s_setprio(1);
#pragma unroll
    for (int ks = 0; ks < 2; ks++) {
      int pc = (ks * 4 + quad) ^ rx;
      short8 bp = *(const short8*)&mypt[r * 64 + pc * 8];
#pragma unroll
      for (int tm = 0; tm < 4; tm++) {
        short8 av = *(const short8*)&v_s[buf][(tm * 16 + r) * 64 + pc * 8];
        o_acc[tm] = __builtin_amdgcn_mfma_f32_16x16x32_bf16(av, bp, o_acc[tm], 0, 0, 0);
      }
    }
    __builtin_amdgcn_s_setprio(0);
  }

  // epilogue: combine l across quads (once), divide, store
  l_lane += __shfl_xor(l_lane, 16);
  l_lane += __shfl_xor(l_lane, 32);
  float inv = 1.0f / l_lane;
  size_t obase = (size_t)(b * N_L + iq) * 1024 + h * 64;
#pragma unroll
  for (int tm = 0; tm < 4; tm++) {
    uint2 pk;
    pk.x = pk2bf(o_acc[tm][0] * inv, o_acc[tm][1] * inv);
    pk.y = pk2bf(o_acc[tm][2] * inv, o_acc[tm][3] * inv);
    *(uint2*)&O[obase + tm * 16 + quad * 4] = pk;
  }
}

// ---------------- launch ----------------

extern "C" void kernel_launch(void* const* d_in, const int* in_sizes, int n_in,
                              void* d_out, int out_size, void* d_ws, size_t ws_size,
                              hipStream_t stream) {
  const float* x = (const float*)d_in[0];
  const float* Wq = (const float*)d_in[1];
  const float* Wk = (const float*)d_in[2];
  const float* Wv = (const float*)d_in[3];
  const float* Wo = (const float*)d_in[4];
  float* out = (float*)d_out;
  char* ws = (char*)d_ws;

  u16* xb    = (u16*)(ws);                // 8 MB  [4096][1024]
  u16* wqkvT = (u16*)(ws + 0x800000);     // 3 MB  [1536][1024]
  u16* woT   = (u16*)(ws + 0xB00000);     // 2 MB  [1024][1024]
  u16* Qb    = (u16*)(ws + 0xD00000);     // 8 MB  [B][H][L][64] (pre-scaled QSCALE)
  u16* Kb    = (u16*)(ws + 0x1500000);    // 2 MB  [B][KvH][L][64]
  u16* Vtb   = (u16*)(ws + 0x1700000);    // 2 MB  [B][KvH][64][L]  (transposed)
  u16* Ob    = (u16*)(ws + 0x1900000);    // 8 MB  [4096][1024]
  float* rc  = (float*)(ws + 0x2100000);  // 256 KB [2048][32]
  float* rs  = (float*)(ws + 0x2140000);  // 256 KB

  prep_kernel<<<3840, 256, 0, stream>>>(x, Wq, Wk, Wv, Wo, xb, wqkvT, woT, rc, rs);
  gemm_kernel<0><<<dim3(12, 32), 256, 0, stream>>>(xb, wqkvT, Qb, Kb, Vtb, nullptr, rc, rs);
  attn_kernel<<<dim3(32, 16, 2), 256, 0, stream>>>(Qb, Kb, Vtb, Ob);
  gemm_kernel<1><<<dim3(8, 64), 256, 0, stream>>>(Ob, woT, nullptr, nullptr, nullptr, out, nullptr, nullptr);
}